// Round 2
// baseline (507.855 us; speedup 1.0000x reference)
//
#include <hip/hip_runtime.h>
#include <hip/hip_bf16.h>

#define DEV_INLINE __device__ __forceinline__

// sh[0..8]: l=0,1,2 real spherical harmonics as in reference _sh (first 9 comps)
static DEV_INLINE void sh_l012(float xx, float yy, float zz, float sh[9]) {
    const float s3  = 1.7320508075688772f;
    const float s5  = 2.23606797749979f;
    const float s15 = 3.872983346207417f;
    float r2 = xx * xx + yy * yy + zz * zz;
    sh[0] = 1.0f;
    sh[1] = s3 * xx;
    sh[2] = s3 * yy;
    sh[3] = s3 * zz;
    sh[4] = s15 * xx * yy;
    sh[5] = s15 * yy * zz;
    sh[6] = 0.5f * s5 * (3.0f * zz * zz - r2);
    sh[7] = s15 * xx * zz;
    sh[8] = 0.5f * s15 * (xx * xx - yy * yy);
}

// w_j[k] = sum_u W1_j[k,u] * W2_j[u] / sqrt(30);  w layout: [0..29]=j0, [30..59]=j1, [60..89]=j2
__global__ void k_w(const float* __restrict__ W1_0,
                    const float* __restrict__ W1_1,
                    const float* __restrict__ W1_2,
                    const float* __restrict__ W2_0,
                    const float* __restrict__ W2_1,
                    const float* __restrict__ W2_2,
                    float* __restrict__ w) {
    const float inv_s30 = 0.18257418583505536f;  // 1/sqrt(30)
    int t = threadIdx.x;
    if (t < 30) {
        float s = 0.f;
        for (int u = 0; u < 64; u++) s += W1_0[t * 64 + u] * W2_0[u];
        w[t] = s * inv_s30;
    } else if (t < 60) {
        int k = t - 30;
        float s = 0.f;
        for (int u = 0; u < 24; u++) s += W1_1[k * 24 + u] * W2_1[u];
        w[30 + k] = s * inv_s30;
    } else if (t < 90) {
        int k = t - 60;
        float s = 0.f;
        for (int u = 0; u < 16; u++) s += W1_2[k * 16 + u] * W2_2[u];
        w[60 + k] = s * inv_s30;
    }
}

// B[v][j] = x[v,:] . w_j  (3 floats per node)
__global__ void k_B(const float* __restrict__ x,
                    const float* __restrict__ w,
                    float* __restrict__ B, int n_nodes) {
    __shared__ float ws[90];
    if (threadIdx.x < 90) ws[threadIdx.x] = w[threadIdx.x];
    __syncthreads();
    int v = blockIdx.x * blockDim.x + threadIdx.x;
    if (v >= n_nodes) return;
    const float* xv = x + (size_t)v * 30;
    float s0 = 0.f, s1 = 0.f, s2 = 0.f;
#pragma unroll
    for (int k = 0; k < 30; k++) {
        float xk = xv[k];
        s0 += xk * ws[k];
        s1 += xk * ws[30 + k];
        s2 += xk * ws[60 + k];
    }
    B[v * 3 + 0] = s0;
    B[v * 3 + 1] = s1;
    B[v * 3 + 2] = s2;
}

// Scatter pass: P[dst][m] += ea * sh[m] * B[src][j(m)]; deg[dst] += 1.
// Also caches ea[e] compactly so pass 2 doesn't re-stream the 24 MB edge_attr.
__global__ void k_edge1(const float* __restrict__ pos,
                        const float* __restrict__ eattr,
                        const int* __restrict__ esrc,
                        const int* __restrict__ edst,
                        const float* __restrict__ B,
                        float* __restrict__ P,
                        int* __restrict__ deg,
                        float* __restrict__ ea_c, int n_edges) {
    int e = blockIdx.x * blockDim.x + threadIdx.x;
    if (e >= n_edges) return;
    int src = esrc[e], dst = edst[e];
    float ea = eattr[(size_t)e * 10];
    ea_c[e] = ea;
    float dx = pos[src * 3 + 0] - pos[dst * 3 + 0];
    float dy = pos[src * 3 + 1] - pos[dst * 3 + 1];
    float dz = pos[src * 3 + 2] - pos[dst * 3 + 2];
    float sh[9];
    sh_l012(dx, dy, dz, sh);
    float b0 = B[src * 3 + 0];
    float b1 = B[src * 3 + 1];
    float b2v = B[src * 3 + 2];
    float* Pd = P + (size_t)dst * 9;
    atomicAdd(Pd + 0, ea * b0);  // sh[0] == 1
#pragma unroll
    for (int m = 1; m < 4; m++) atomicAdd(Pd + m, ea * sh[m] * b1);
#pragma unroll
    for (int m = 4; m < 9; m++) atomicAdd(Pd + m, ea * sh[m] * b2v);
    atomicAdd(deg + dst, 1);
}

// Per-node: isd = deg>0 ? rsqrt(deg) : 0; P[v] *= isd (folds the g = n[src]*isd factor);
// also count atoms per molecule.
__global__ void k_node1(float* __restrict__ P,
                        const int* __restrict__ deg,
                        float* __restrict__ isd,
                        const int* __restrict__ batch,
                        int* __restrict__ atoms, int n_nodes) {
    int v = blockIdx.x * blockDim.x + threadIdx.x;
    if (v >= n_nodes) return;
    int d = deg[v];
    float s = (d > 0) ? rsqrtf((float)d) : 0.f;
    isd[v] = s;
    float* Pv = P + (size_t)v * 9;
#pragma unroll
    for (int m = 0; m < 9; m++) Pv[m] *= s;
    atomicAdd(atoms + batch[v], 1);
}

// Gather pass: out_e = ea * (P0 + (1/sqrt3)*sum sh[1..3]P[1..3] + (1/sqrt5)*sum sh[4..8]P[4..8]) / sqrt(104)
// scattered to node_acc[dst].
__global__ void k_edge2(const float* __restrict__ pos,
                        const float* __restrict__ ea_c,
                        const int* __restrict__ esrc,
                        const int* __restrict__ edst,
                        const float* __restrict__ P,
                        float* __restrict__ node_acc, int n_edges) {
    int e = blockIdx.x * blockDim.x + threadIdx.x;
    if (e >= n_edges) return;
    int src = esrc[e], dst = edst[e];
    float ea = ea_c[e];
    float dx = pos[src * 3 + 0] - pos[dst * 3 + 0];
    float dy = pos[src * 3 + 1] - pos[dst * 3 + 1];
    float dz = pos[src * 3 + 2] - pos[dst * 3 + 2];
    float sh[9];
    sh_l012(dx, dy, dz, sh);
    const float* Ps = P + (size_t)src * 9;
    float t0 = Ps[0];  // sh[0] == 1
    float t1 = sh[1] * Ps[1] + sh[2] * Ps[2] + sh[3] * Ps[3];
    float t2 = sh[4] * Ps[4] + sh[5] * Ps[5] + sh[6] * Ps[6] + sh[7] * Ps[7] + sh[8] * Ps[8];
    const float i3 = 0.5773502691896258f;     // 1/sqrt(3)
    const float i5 = 0.4472135954999579f;     // 1/sqrt(5)
    const float i104 = 0.09805806756909202f;  // 1/sqrt(104)
    atomicAdd(node_acc + dst, ea * (t0 + t1 * i3 + t2 * i5) * i104);
}

// acc[mol] += node_acc[v] * isd[v]
__global__ void k_node2(const float* __restrict__ node_acc,
                        const float* __restrict__ isd,
                        const int* __restrict__ batch,
                        float* __restrict__ acc, int n_nodes) {
    int v = blockIdx.x * blockDim.x + threadIdx.x;
    if (v >= n_nodes) return;
    atomicAdd(acc + batch[v], node_acc[v] * isd[v]);
}

__global__ void k_final(const float* __restrict__ acc,
                        const int* __restrict__ atoms,
                        float* __restrict__ out, int n_mol) {
    int m = blockIdx.x * blockDim.x + threadIdx.x;
    if (m >= n_mol) return;
    int a = atoms[m];
    float v = (a > 0) ? acc[m] * rsqrtf((float)a) : 0.f;
    out[m] = v;
}

extern "C" void kernel_launch(void* const* d_in, const int* in_sizes, int n_in,
                              void* d_out, int out_size, void* d_ws, size_t ws_size,
                              hipStream_t stream) {
    const float* pos   = (const float*)d_in[0];
    const float* x     = (const float*)d_in[1];
    const float* eattr = (const float*)d_in[2];
    const float* W1_0  = (const float*)d_in[3];
    const float* W1_1  = (const float*)d_in[4];
    const float* W1_2  = (const float*)d_in[5];
    const float* W2_0  = (const float*)d_in[6];
    const float* W2_1  = (const float*)d_in[7];
    const float* W2_2  = (const float*)d_in[8];
    const int* esrc  = (const int*)d_in[9];
    const int* edst  = (const int*)d_in[10];
    const int* batch = (const int*)d_in[11];

    const int n_edges = in_sizes[9];       // 600000
    const int n_nodes = in_sizes[11];      // 50000
    const int n_mol   = out_size;          // 512
    float* out = (float*)d_out;

    // Workspace layout (256B-aligned regions). Zeroed regions come first.
    char* ws = (char*)d_ws;
    size_t off = 0;
    auto carve = [&](size_t bytes) {
        size_t o = off;
        off = (off + bytes + 255) & ~(size_t)255;
        return o;
    };
    size_t off_P        = carve((size_t)n_nodes * 9 * sizeof(float));
    size_t off_deg      = carve((size_t)n_nodes * sizeof(int));
    size_t off_node_acc = carve((size_t)n_nodes * sizeof(float));
    size_t off_acc      = carve((size_t)n_mol * sizeof(float));
    size_t off_atoms    = carve((size_t)n_mol * sizeof(int));
    size_t zero_bytes   = off;  // everything above must start at 0
    size_t off_isd      = carve((size_t)n_nodes * sizeof(float));
    size_t off_w        = carve(90 * sizeof(float));
    size_t off_B        = carve((size_t)n_nodes * 3 * sizeof(float));
    size_t off_ea       = carve((size_t)n_edges * sizeof(float));
    (void)ws_size;

    float* P        = (float*)(ws + off_P);
    int*   deg      = (int*)(ws + off_deg);
    float* node_acc = (float*)(ws + off_node_acc);
    float* acc      = (float*)(ws + off_acc);
    int*   atoms    = (int*)(ws + off_atoms);
    float* isd      = (float*)(ws + off_isd);
    float* w        = (float*)(ws + off_w);
    float* B        = (float*)(ws + off_B);
    float* ea_c     = (float*)(ws + off_ea);

    hipMemsetAsync(d_ws, 0, zero_bytes, stream);

    const int BS = 256;
    k_w<<<1, 128, 0, stream>>>(W1_0, W1_1, W1_2, W2_0, W2_1, W2_2, w);
    k_B<<<(n_nodes + BS - 1) / BS, BS, 0, stream>>>(x, w, B, n_nodes);
    k_edge1<<<(n_edges + BS - 1) / BS, BS, 0, stream>>>(pos, eattr, esrc, edst, B, P, deg, ea_c, n_edges);
    k_node1<<<(n_nodes + BS - 1) / BS, BS, 0, stream>>>(P, deg, isd, batch, atoms, n_nodes);
    k_edge2<<<(n_edges + BS - 1) / BS, BS, 0, stream>>>(pos, ea_c, esrc, edst, P, node_acc, n_edges);
    k_node2<<<(n_nodes + BS - 1) / BS, BS, 0, stream>>>(node_acc, isd, batch, acc, n_nodes);
    k_final<<<(n_mol + BS - 1) / BS, BS, 0, stream>>>(acc, atoms, out, n_mol);
}

// Round 3
// 256.986 us; speedup vs baseline: 1.9762x; 1.9762x over previous
//
#include <hip/hip_runtime.h>

#define DEV_INLINE __device__ __forceinline__

// sh[0..8]: l=0,1,2 real spherical harmonics as in reference _sh (first 9 comps)
static DEV_INLINE void sh_l012(float xx, float yy, float zz, float sh[9]) {
    const float s3  = 1.7320508075688772f;
    const float s5  = 2.23606797749979f;
    const float s15 = 3.872983346207417f;
    float r2 = xx * xx + yy * yy + zz * zz;
    sh[0] = 1.0f;
    sh[1] = s3 * xx;
    sh[2] = s3 * yy;
    sh[3] = s3 * zz;
    sh[4] = s15 * xx * yy;
    sh[5] = s15 * yy * zz;
    sh[6] = 0.5f * s5 * (3.0f * zz * zz - r2);
    sh[7] = s15 * xx * zz;
    sh[8] = 0.5f * s15 * (xx * xx - yy * yy);
}

// w_j[k] = sum_u W1_j[k,u] * W2_j[u] / sqrt(30);  w: [0..29]=j0, [30..59]=j1, [60..89]=j2
__global__ void k_w(const float* __restrict__ W1_0, const float* __restrict__ W1_1,
                    const float* __restrict__ W1_2, const float* __restrict__ W2_0,
                    const float* __restrict__ W2_1, const float* __restrict__ W2_2,
                    float* __restrict__ w) {
    const float inv_s30 = 0.18257418583505536f;
    int t = threadIdx.x;
    if (t < 30) {
        float s = 0.f;
        for (int u = 0; u < 64; u++) s += W1_0[t * 64 + u] * W2_0[u];
        w[t] = s * inv_s30;
    } else if (t < 60) {
        int k = t - 30;
        float s = 0.f;
        for (int u = 0; u < 24; u++) s += W1_1[k * 24 + u] * W2_1[u];
        w[30 + k] = s * inv_s30;
    } else if (t < 90) {
        int k = t - 60;
        float s = 0.f;
        for (int u = 0; u < 16; u++) s += W1_2[k * 16 + u] * W2_2[u];
        w[60 + k] = s * inv_s30;
    }
}

// B[v][j] = x[v,:] . w_j  (3 floats per node)
__global__ void k_B(const float* __restrict__ x, const float* __restrict__ w,
                    float* __restrict__ B, int n_nodes) {
    __shared__ float ws[90];
    if (threadIdx.x < 90) ws[threadIdx.x] = w[threadIdx.x];
    __syncthreads();
    int v = blockIdx.x * blockDim.x + threadIdx.x;
    if (v >= n_nodes) return;
    const float* xv = x + (size_t)v * 30;
    float s0 = 0.f, s1 = 0.f, s2 = 0.f;
#pragma unroll
    for (int k = 0; k < 30; k++) {
        float xk = xv[k];
        s0 += xk * ws[k];
        s1 += xk * ws[30 + k];
        s2 += xk * ws[60 + k];
    }
    B[v * 3 + 0] = s0;
    B[v * 3 + 1] = s1;
    B[v * 3 + 2] = s2;
}

__global__ void k_deg(const int* __restrict__ edst, int* __restrict__ deg, int n_edges) {
    int e = blockIdx.x * blockDim.x + threadIdx.x;
    if (e >= n_edges) return;
    atomicAdd(deg + edst[e], 1);
}

// blocksum[b] = sum of deg over block b's 256 nodes
__global__ void k_scan1(const int* __restrict__ deg, int* __restrict__ blocksum, int n_nodes) {
    __shared__ int s[256];
    int t = threadIdx.x;
    int v = blockIdx.x * 256 + t;
    s[t] = (v < n_nodes) ? deg[v] : 0;
    __syncthreads();
    for (int off = 128; off > 0; off >>= 1) {
        if (t < off) s[t] += s[t + off];
        __syncthreads();
    }
    if (t == 0) blocksum[blockIdx.x] = s[0];
}

// exclusive scan of blocksum (nb <= 256) -> blockoff
__global__ void k_scan2(const int* __restrict__ blocksum, int* __restrict__ blockoff, int nb) {
    __shared__ int s[256];
    int t = threadIdx.x;
    int val = (t < nb) ? blocksum[t] : 0;
    s[t] = val;
    __syncthreads();
    for (int off = 1; off < 256; off <<= 1) {
        int y = (t >= off) ? s[t - off] : 0;
        __syncthreads();
        s[t] += y;
        __syncthreads();
    }
    if (t < nb) blockoff[t] = s[t] - val;
}

// rowptr[v] = blockoff[b] + exclusive-scan-within-block(deg)
__global__ void k_scan3(const int* __restrict__ deg, const int* __restrict__ blockoff,
                        int* __restrict__ rowptr, int n_nodes) {
    __shared__ int s[256];
    int t = threadIdx.x;
    int v = blockIdx.x * 256 + t;
    int val = (v < n_nodes) ? deg[v] : 0;
    s[t] = val;
    __syncthreads();
    for (int off = 1; off < 256; off <<= 1) {
        int y = (t >= off) ? s[t - off] : 0;
        __syncthreads();
        s[t] += y;
        __syncthreads();
    }
    if (v < n_nodes) rowptr[v] = blockoff[blockIdx.x] + s[t] - val;
}

// slot = rowptr[dst] + cursor[dst]++;  rec[slot] = {src, ea}
__global__ void k_place(const float* __restrict__ eattr, const int* __restrict__ esrc,
                        const int* __restrict__ edst, const int* __restrict__ rowptr,
                        int* __restrict__ cursor, int2* __restrict__ rec, int n_edges) {
    int e = blockIdx.x * blockDim.x + threadIdx.x;
    if (e >= n_edges) return;
    int dst = edst[e];
    int slot = rowptr[dst] + atomicAdd(cursor + dst, 1);
    int2 r;
    r.x = esrc[e];
    r.y = __float_as_int(eattr[(size_t)e * 10]);
    rec[slot] = r;
}

// Pass A: per dst node, accumulate P[v][m] = isd * sum_e ea*sh[m]*B_j[src]; count atoms/mol
__global__ void k_passA(const float* __restrict__ pos, const int2* __restrict__ rec,
                        const int* __restrict__ rowptr, const int* __restrict__ deg,
                        const float* __restrict__ B, const int* __restrict__ batch,
                        float* __restrict__ P, int* __restrict__ atoms, int n_nodes) {
    int v = blockIdx.x * blockDim.x + threadIdx.x;
    if (v >= n_nodes) return;
    int beg = rowptr[v], d = deg[v];
    float px = pos[v * 3 + 0], py = pos[v * 3 + 1], pz = pos[v * 3 + 2];
    float acc[9];
#pragma unroll
    for (int m = 0; m < 9; m++) acc[m] = 0.f;
    for (int i = beg; i < beg + d; i++) {
        int2 r = rec[i];
        int src = r.x;
        float ea = __int_as_float(r.y);
        float dx = pos[src * 3 + 0] - px;
        float dy = pos[src * 3 + 1] - py;
        float dz = pos[src * 3 + 2] - pz;
        float sh[9];
        sh_l012(dx, dy, dz, sh);
        float b0 = B[src * 3 + 0], b1 = B[src * 3 + 1], b2 = B[src * 3 + 2];
        acc[0] += ea * b0;  // sh[0]==1
#pragma unroll
        for (int m = 1; m < 4; m++) acc[m] += ea * sh[m] * b1;
#pragma unroll
        for (int m = 4; m < 9; m++) acc[m] += ea * sh[m] * b2;
    }
    float s = (d > 0) ? rsqrtf((float)d) : 0.f;
    float* Pv = P + (size_t)v * 9;
#pragma unroll
    for (int m = 0; m < 9; m++) Pv[m] = acc[m] * s;
    atomicAdd(atoms + batch[v], 1);
}

// Pass B: per dst node, out contribution = isd[v]*sum_e ea*(P0+ (1/s3)sum shP + (1/s5)sum shP)/s104
__global__ void k_passB(const float* __restrict__ pos, const int2* __restrict__ rec,
                        const int* __restrict__ rowptr, const int* __restrict__ deg,
                        const float* __restrict__ P, const int* __restrict__ batch,
                        float* __restrict__ accmol, int n_nodes) {
    int v = blockIdx.x * blockDim.x + threadIdx.x;
    if (v >= n_nodes) return;
    int beg = rowptr[v], d = deg[v];
    float px = pos[v * 3 + 0], py = pos[v * 3 + 1], pz = pos[v * 3 + 2];
    const float i3 = 0.5773502691896258f;     // 1/sqrt(3)
    const float i5 = 0.4472135954999579f;     // 1/sqrt(5)
    const float i104 = 0.09805806756909202f;  // 1/sqrt(104)
    float s = 0.f;
    for (int i = beg; i < beg + d; i++) {
        int2 r = rec[i];
        int src = r.x;
        float ea = __int_as_float(r.y);
        float dx = pos[src * 3 + 0] - px;
        float dy = pos[src * 3 + 1] - py;
        float dz = pos[src * 3 + 2] - pz;
        float sh[9];
        sh_l012(dx, dy, dz, sh);
        const float* Ps = P + (size_t)src * 9;
        float t0 = Ps[0];
        float t1 = sh[1] * Ps[1] + sh[2] * Ps[2] + sh[3] * Ps[3];
        float t2 = sh[4] * Ps[4] + sh[5] * Ps[5] + sh[6] * Ps[6] + sh[7] * Ps[7] + sh[8] * Ps[8];
        s += ea * (t0 + t1 * i3 + t2 * i5);
    }
    float isd = (d > 0) ? rsqrtf((float)d) : 0.f;
    atomicAdd(accmol + batch[v], s * i104 * isd);
}

__global__ void k_final(const float* __restrict__ acc, const int* __restrict__ atoms,
                        float* __restrict__ out, int n_mol) {
    int m = blockIdx.x * blockDim.x + threadIdx.x;
    if (m >= n_mol) return;
    int a = atoms[m];
    out[m] = (a > 0) ? acc[m] * rsqrtf((float)a) : 0.f;
}

extern "C" void kernel_launch(void* const* d_in, const int* in_sizes, int n_in,
                              void* d_out, int out_size, void* d_ws, size_t ws_size,
                              hipStream_t stream) {
    const float* pos   = (const float*)d_in[0];
    const float* x     = (const float*)d_in[1];
    const float* eattr = (const float*)d_in[2];
    const float* W1_0  = (const float*)d_in[3];
    const float* W1_1  = (const float*)d_in[4];
    const float* W1_2  = (const float*)d_in[5];
    const float* W2_0  = (const float*)d_in[6];
    const float* W2_1  = (const float*)d_in[7];
    const float* W2_2  = (const float*)d_in[8];
    const int* esrc  = (const int*)d_in[9];
    const int* edst  = (const int*)d_in[10];
    const int* batch = (const int*)d_in[11];

    const int n_edges = in_sizes[9];       // 600000
    const int n_nodes = in_sizes[11];      // 50000
    const int n_mol   = out_size;          // 512
    float* out = (float*)d_out;

    const int BS = 256;
    const int NB = (n_nodes + BS - 1) / BS;  // 196 (must be <= 256 for k_scan2)
    const int EB = (n_edges + BS - 1) / BS;

    // Workspace layout; zeroed regions first.
    char* ws = (char*)d_ws;
    size_t off = 0;
    auto carve = [&](size_t bytes) {
        size_t o = off;
        off = (off + bytes + 255) & ~(size_t)255;
        return o;
    };
    size_t off_deg    = carve((size_t)n_nodes * sizeof(int));
    size_t off_cur    = carve((size_t)n_nodes * sizeof(int));
    size_t off_acc    = carve((size_t)n_mol * sizeof(float));
    size_t off_atoms  = carve((size_t)n_mol * sizeof(int));
    size_t zero_bytes = off;
    size_t off_rowptr = carve((size_t)n_nodes * sizeof(int));
    size_t off_bsum   = carve((size_t)NB * sizeof(int));
    size_t off_boff   = carve((size_t)NB * sizeof(int));
    size_t off_w      = carve(90 * sizeof(float));
    size_t off_B      = carve((size_t)n_nodes * 3 * sizeof(float));
    size_t off_P      = carve((size_t)n_nodes * 9 * sizeof(float));
    size_t off_rec    = carve((size_t)n_edges * sizeof(int2));
    (void)ws_size;

    int*   deg    = (int*)(ws + off_deg);
    int*   cursor = (int*)(ws + off_cur);
    float* accmol = (float*)(ws + off_acc);
    int*   atoms  = (int*)(ws + off_atoms);
    int*   rowptr = (int*)(ws + off_rowptr);
    int*   bsum   = (int*)(ws + off_bsum);
    int*   boff   = (int*)(ws + off_boff);
    float* w      = (float*)(ws + off_w);
    float* B      = (float*)(ws + off_B);
    float* P      = (float*)(ws + off_P);
    int2*  rec    = (int2*)(ws + off_rec);

    hipMemsetAsync(d_ws, 0, zero_bytes, stream);

    k_w<<<1, 128, 0, stream>>>(W1_0, W1_1, W1_2, W2_0, W2_1, W2_2, w);
    k_B<<<NB, BS, 0, stream>>>(x, w, B, n_nodes);
    k_deg<<<EB, BS, 0, stream>>>(edst, deg, n_edges);
    k_scan1<<<NB, BS, 0, stream>>>(deg, bsum, n_nodes);
    k_scan2<<<1, 256, 0, stream>>>(bsum, boff, NB);
    k_scan3<<<NB, BS, 0, stream>>>(deg, boff, rowptr, n_nodes);
    k_place<<<EB, BS, 0, stream>>>(eattr, esrc, edst, rowptr, cursor, rec, n_edges);
    k_passA<<<NB, BS, 0, stream>>>(pos, rec, rowptr, deg, B, batch, P, atoms, n_nodes);
    k_passB<<<NB, BS, 0, stream>>>(pos, rec, rowptr, deg, P, batch, accmol, n_nodes);
    k_final<<<(n_mol + BS - 1) / BS, BS, 0, stream>>>(accmol, atoms, out, n_mol);
}

// Round 4
// 184.788 us; speedup vs baseline: 2.7483x; 1.3907x over previous
//
#include <hip/hip_runtime.h>

#define DEV_INLINE __device__ __forceinline__

// sh[0..8]: l=0,1,2 real spherical harmonics as in reference _sh (first 9 comps)
static DEV_INLINE void sh_l012(float xx, float yy, float zz, float sh[9]) {
    const float s3  = 1.7320508075688772f;
    const float s5  = 2.23606797749979f;
    const float s15 = 3.872983346207417f;
    float r2 = xx * xx + yy * yy + zz * zz;
    sh[0] = 1.0f;
    sh[1] = s3 * xx;
    sh[2] = s3 * yy;
    sh[3] = s3 * zz;
    sh[4] = s15 * xx * yy;
    sh[5] = s15 * yy * zz;
    sh[6] = 0.5f * s5 * (3.0f * zz * zz - r2);
    sh[7] = s15 * xx * zz;
    sh[8] = 0.5f * s15 * (xx * xx - yy * yy);
}

// Fused: w (per-block recompute), B[v] = x[v].w_j, pos4 packing, deg histogram (2 edges/thread).
__global__ void k_prep(const float* __restrict__ x,
                       const float* __restrict__ pos,
                       const float* __restrict__ W1_0, const float* __restrict__ W1_1,
                       const float* __restrict__ W1_2, const float* __restrict__ W2_0,
                       const float* __restrict__ W2_1, const float* __restrict__ W2_2,
                       const int* __restrict__ edst,
                       float* __restrict__ B, float4* __restrict__ pos4,
                       int* __restrict__ deg, int n_nodes, int n_edges) {
    __shared__ float ws[90];
    int t = threadIdx.x;
    int g = blockIdx.x * blockDim.x + t;
    bool nodeBlock = (blockIdx.x * blockDim.x) < n_nodes;
    if (nodeBlock) {
        const float inv_s30 = 0.18257418583505536f;
        if (t < 30) {
            float s = 0.f;
            for (int u = 0; u < 64; u++) s += W1_0[t * 64 + u] * W2_0[u];
            ws[t] = s * inv_s30;
        } else if (t < 60) {
            int k = t - 30;
            float s = 0.f;
            for (int u = 0; u < 24; u++) s += W1_1[k * 24 + u] * W2_1[u];
            ws[t] = s * inv_s30;
        } else if (t < 90) {
            int k = t - 60;
            float s = 0.f;
            for (int u = 0; u < 16; u++) s += W1_2[k * 16 + u] * W2_2[u];
            ws[t] = s * inv_s30;
        }
        __syncthreads();
        if (g < n_nodes) {
            const float* xv = x + (size_t)g * 30;
            float s0 = 0.f, s1 = 0.f, s2 = 0.f;
#pragma unroll
            for (int k = 0; k < 30; k++) {
                float xk = xv[k];
                s0 += xk * ws[k];
                s1 += xk * ws[30 + k];
                s2 += xk * ws[60 + k];
            }
            B[g * 3 + 0] = s0;
            B[g * 3 + 1] = s1;
            B[g * 3 + 2] = s2;
            pos4[g] = make_float4(pos[g * 3 + 0], pos[g * 3 + 1], pos[g * 3 + 2], 0.f);
        }
    }
    int e0 = 2 * g, e1 = 2 * g + 1;
    if (e1 < n_edges) {
        int2 d2 = ((const int2*)edst)[g];
        atomicAdd(deg + d2.x, 1);
        atomicAdd(deg + d2.y, 1);
    } else if (e0 < n_edges) {
        atomicAdd(deg + edst[e0], 1);
    }
}

// blocksum[b] = sum of deg over block b's 256 nodes
__global__ void k_scan1(const int* __restrict__ deg, int* __restrict__ blocksum, int n_nodes) {
    __shared__ int s[256];
    int t = threadIdx.x;
    int v = blockIdx.x * 256 + t;
    s[t] = (v < n_nodes) ? deg[v] : 0;
    __syncthreads();
    for (int off = 128; off > 0; off >>= 1) {
        if (t < off) s[t] += s[t + off];
        __syncthreads();
    }
    if (t == 0) blocksum[blockIdx.x] = s[0];
}

// exclusive scan of blocksum (nb <= 256) -> blockoff
__global__ void k_scan2(const int* __restrict__ blocksum, int* __restrict__ blockoff, int nb) {
    __shared__ int s[256];
    int t = threadIdx.x;
    int val = (t < nb) ? blocksum[t] : 0;
    s[t] = val;
    __syncthreads();
    for (int off = 1; off < 256; off <<= 1) {
        int y = (t >= off) ? s[t - off] : 0;
        __syncthreads();
        s[t] += y;
        __syncthreads();
    }
    if (t < nb) blockoff[t] = s[t] - val;
}

// rowptr[v] = blockoff[b] + exclusive-scan-within-block(deg); also atoms histogram (batch sorted)
__global__ void k_scan3(const int* __restrict__ deg, const int* __restrict__ blockoff,
                        int* __restrict__ rowptr, const int* __restrict__ batch,
                        int* __restrict__ atoms, int n_nodes) {
    __shared__ int s[256];
    __shared__ int hist[256];
    int t = threadIdx.x;
    int v = blockIdx.x * 256 + t;
    int val = (v < n_nodes) ? deg[v] : 0;
    s[t] = val;
    hist[t] = 0;
    __syncthreads();
    for (int off = 1; off < 256; off <<= 1) {
        int y = (t >= off) ? s[t - off] : 0;
        __syncthreads();
        s[t] += y;
        __syncthreads();
    }
    if (v < n_nodes) rowptr[v] = blockoff[blockIdx.x] + s[t] - val;
    // atoms-per-mol via block-local histogram (batch is sorted => small mol range per block)
    int v0 = blockIdx.x * 256;
    if (v0 < n_nodes) {
        int molFirst = batch[v0];
        int vend = min(v0 + 255, n_nodes - 1);
        int molLast = batch[vend];
        if (v < n_nodes) atomicAdd(&hist[batch[v] - molFirst], 1);
        __syncthreads();
        if (t <= molLast - molFirst) atomicAdd(atoms + molFirst + t, hist[t]);
    }
}

// slot = rowptr[dst] + cursor[dst]++;  rec[slot] = {src, ea}   (2 edges/thread)
__global__ void k_place(const float* __restrict__ eattr, const int* __restrict__ esrc,
                        const int* __restrict__ edst, const int* __restrict__ rowptr,
                        int* __restrict__ cursor, int2* __restrict__ rec, int n_edges) {
    int g = blockIdx.x * blockDim.x + threadIdx.x;
    int e0 = 2 * g, e1 = 2 * g + 1;
    if (e1 < n_edges) {
        int2 d2 = ((const int2*)edst)[g];
        int2 s2 = ((const int2*)esrc)[g];
        float ea0 = eattr[(size_t)e0 * 10];
        float ea1 = eattr[(size_t)e1 * 10];
        int slot0 = rowptr[d2.x] + atomicAdd(cursor + d2.x, 1);
        int slot1 = rowptr[d2.y] + atomicAdd(cursor + d2.y, 1);
        rec[slot0] = make_int2(s2.x, __float_as_int(ea0));
        rec[slot1] = make_int2(s2.y, __float_as_int(ea1));
    } else if (e0 < n_edges) {
        int dst = edst[e0];
        int slot = rowptr[dst] + atomicAdd(cursor + dst, 1);
        rec[slot] = make_int2(esrc[e0], __float_as_int(eattr[(size_t)e0 * 10]));
    }
}

// Pass A: 4 lanes per dst node; P[v][0..8] = isd * sum_e ea*sh[m]*B_j[src]; P stride 12 floats.
__global__ void k_passA(const float4* __restrict__ pos4, const int2* __restrict__ rec,
                        const int* __restrict__ rowptr, const int* __restrict__ deg,
                        const float* __restrict__ B,
                        float* __restrict__ P, int n_nodes) {
    int g = blockIdx.x * blockDim.x + threadIdx.x;
    int v = g >> 2, r = g & 3;
    if (v >= n_nodes) return;
    int beg = rowptr[v], d = deg[v];
    float4 pv = pos4[v];
    float acc[9];
#pragma unroll
    for (int m = 0; m < 9; m++) acc[m] = 0.f;
    for (int i = beg + r; i < beg + d; i += 4) {
        int2 rcd = rec[i];
        int src = rcd.x;
        float ea = __int_as_float(rcd.y);
        float4 ps = pos4[src];
        float dx = ps.x - pv.x, dy = ps.y - pv.y, dz = ps.z - pv.z;
        float sh[9];
        sh_l012(dx, dy, dz, sh);
        float b0 = B[src * 3 + 0], b1 = B[src * 3 + 1], b2 = B[src * 3 + 2];
        acc[0] += ea * b0;  // sh[0]==1
#pragma unroll
        for (int m = 1; m < 4; m++) acc[m] += ea * sh[m] * b1;
#pragma unroll
        for (int m = 4; m < 9; m++) acc[m] += ea * sh[m] * b2;
    }
#pragma unroll
    for (int off = 1; off < 4; off <<= 1)
#pragma unroll
        for (int m = 0; m < 9; m++) acc[m] += __shfl_xor(acc[m], off);
    if (r == 0) {
        float s = (d > 0) ? rsqrtf((float)d) : 0.f;
        float* Pv = P + (size_t)v * 12;
        *(float4*)(Pv + 0) = make_float4(acc[0] * s, acc[1] * s, acc[2] * s, acc[3] * s);
        *(float4*)(Pv + 4) = make_float4(acc[4] * s, acc[5] * s, acc[6] * s, acc[7] * s);
        Pv[8] = acc[8] * s;
    }
}

// Pass B: 4 lanes per dst node; per-block LDS mol aggregation (batch sorted), then flush.
__global__ void k_passB(const float4* __restrict__ pos4, const int2* __restrict__ rec,
                        const int* __restrict__ rowptr, const int* __restrict__ deg,
                        const float* __restrict__ P, const int* __restrict__ batch,
                        float* __restrict__ accmol, int n_nodes) {
    __shared__ float smol[64];
    int t = threadIdx.x;
    int g = blockIdx.x * blockDim.x + t;
    int v = g >> 2, r = g & 3;
    int v0 = (blockIdx.x * blockDim.x) >> 2;  // first node of block (64 nodes/block)
    if (t < 64) smol[t] = 0.f;
    __syncthreads();
    const float i3 = 0.5773502691896258f;     // 1/sqrt(3)
    const float i5 = 0.4472135954999579f;     // 1/sqrt(5)
    const float i104 = 0.09805806756909202f;  // 1/sqrt(104)
    int molFirst = batch[min(v0, n_nodes - 1)];
    if (v < n_nodes) {
        int beg = rowptr[v], d = deg[v];
        float4 pv = pos4[v];
        float s = 0.f;
        for (int i = beg + r; i < beg + d; i += 4) {
            int2 rcd = rec[i];
            int src = rcd.x;
            float ea = __int_as_float(rcd.y);
            float4 ps = pos4[src];
            float dx = ps.x - pv.x, dy = ps.y - pv.y, dz = ps.z - pv.z;
            float sh[9];
            sh_l012(dx, dy, dz, sh);
            const float* Ps = P + (size_t)src * 12;
            float4 p03 = *(const float4*)(Ps + 0);
            float4 p47 = *(const float4*)(Ps + 4);
            float p8 = Ps[8];
            float t1 = sh[1] * p03.y + sh[2] * p03.z + sh[3] * p03.w;
            float t2 = sh[4] * p47.x + sh[5] * p47.y + sh[6] * p47.z + sh[7] * p47.w + sh[8] * p8;
            s += ea * (p03.x + t1 * i3 + t2 * i5);
        }
#pragma unroll
        for (int off = 1; off < 4; off <<= 1) s += __shfl_xor(s, off);
        if (r == 0) {
            float isd = (d > 0) ? rsqrtf((float)d) : 0.f;
            atomicAdd(&smol[batch[v] - molFirst], s * i104 * isd);
        }
    }
    __syncthreads();
    int vend = min(v0 + 63, n_nodes - 1);
    int nm = batch[vend] - molFirst + 1;
    if (t < nm) {
        float val = smol[t];
        if (val != 0.f) atomicAdd(accmol + molFirst + t, val);
    }
}

__global__ void k_final(const float* __restrict__ acc, const int* __restrict__ atoms,
                        float* __restrict__ out, int n_mol) {
    int m = blockIdx.x * blockDim.x + threadIdx.x;
    if (m >= n_mol) return;
    int a = atoms[m];
    out[m] = (a > 0) ? acc[m] * rsqrtf((float)a) : 0.f;
}

extern "C" void kernel_launch(void* const* d_in, const int* in_sizes, int n_in,
                              void* d_out, int out_size, void* d_ws, size_t ws_size,
                              hipStream_t stream) {
    const float* pos   = (const float*)d_in[0];
    const float* x     = (const float*)d_in[1];
    const float* eattr = (const float*)d_in[2];
    const float* W1_0  = (const float*)d_in[3];
    const float* W1_1  = (const float*)d_in[4];
    const float* W1_2  = (const float*)d_in[5];
    const float* W2_0  = (const float*)d_in[6];
    const float* W2_1  = (const float*)d_in[7];
    const float* W2_2  = (const float*)d_in[8];
    const int* esrc  = (const int*)d_in[9];
    const int* edst  = (const int*)d_in[10];
    const int* batch = (const int*)d_in[11];

    const int n_edges = in_sizes[9];       // 600000
    const int n_nodes = in_sizes[11];      // 50000
    const int n_mol   = out_size;          // 512
    float* out = (float*)d_out;

    const int BS = 256;
    const int NB = (n_nodes + BS - 1) / BS;            // 196 (<= 256 for k_scan2)
    const int EB2 = (n_edges / 2 + BS - 1) / BS;       // 2 edges/thread
    const int VB = (4 * n_nodes + BS - 1) / BS;        // 4 lanes/node

    // Workspace layout; zeroed regions first.
    char* ws = (char*)d_ws;
    size_t off = 0;
    auto carve = [&](size_t bytes) {
        size_t o = off;
        off = (off + bytes + 255) & ~(size_t)255;
        return o;
    };
    size_t off_deg    = carve((size_t)n_nodes * sizeof(int));
    size_t off_cur    = carve((size_t)n_nodes * sizeof(int));
    size_t off_acc    = carve((size_t)n_mol * sizeof(float));
    size_t off_atoms  = carve((size_t)n_mol * sizeof(int));
    size_t zero_bytes = off;
    size_t off_rowptr = carve((size_t)n_nodes * sizeof(int));
    size_t off_bsum   = carve((size_t)NB * sizeof(int));
    size_t off_boff   = carve((size_t)NB * sizeof(int));
    size_t off_B      = carve((size_t)n_nodes * 3 * sizeof(float));
    size_t off_P      = carve((size_t)n_nodes * 12 * sizeof(float));  // padded 48B stride
    size_t off_pos4   = carve((size_t)n_nodes * sizeof(float4));
    size_t off_rec    = carve((size_t)n_edges * sizeof(int2));
    (void)ws_size;

    int*    deg    = (int*)(ws + off_deg);
    int*    cursor = (int*)(ws + off_cur);
    float*  accmol = (float*)(ws + off_acc);
    int*    atoms  = (int*)(ws + off_atoms);
    int*    rowptr = (int*)(ws + off_rowptr);
    int*    bsum   = (int*)(ws + off_bsum);
    int*    boff   = (int*)(ws + off_boff);
    float*  B      = (float*)(ws + off_B);
    float*  P      = (float*)(ws + off_P);
    float4* pos4   = (float4*)(ws + off_pos4);
    int2*   rec    = (int2*)(ws + off_rec);

    hipMemsetAsync(d_ws, 0, zero_bytes, stream);

    k_prep<<<EB2, BS, 0, stream>>>(x, pos, W1_0, W1_1, W1_2, W2_0, W2_1, W2_2,
                                   edst, B, pos4, deg, n_nodes, n_edges);
    k_scan1<<<NB, BS, 0, stream>>>(deg, bsum, n_nodes);
    k_scan2<<<1, 256, 0, stream>>>(bsum, boff, NB);
    k_scan3<<<NB, BS, 0, stream>>>(deg, boff, rowptr, batch, atoms, n_nodes);
    k_place<<<EB2, BS, 0, stream>>>(eattr, esrc, edst, rowptr, cursor, rec, n_edges);
    k_passA<<<VB, BS, 0, stream>>>(pos4, rec, rowptr, deg, B, P, n_nodes);
    k_passB<<<VB, BS, 0, stream>>>(pos4, rec, rowptr, deg, P, batch, accmol, n_nodes);
    k_final<<<(n_mol + BS - 1) / BS, BS, 0, stream>>>(accmol, atoms, out, n_mol);
}

// Round 5
// 181.459 us; speedup vs baseline: 2.7987x; 1.0183x over previous
//
#include <hip/hip_runtime.h>

#define DEV_INLINE __device__ __forceinline__

// sh[0..8]: l=0,1,2 real spherical harmonics as in reference _sh (first 9 comps)
static DEV_INLINE void sh_l012(float xx, float yy, float zz, float sh[9]) {
    const float s3  = 1.7320508075688772f;
    const float s5  = 2.23606797749979f;
    const float s15 = 3.872983346207417f;
    float r2 = xx * xx + yy * yy + zz * zz;
    sh[0] = 1.0f;
    sh[1] = s3 * xx;
    sh[2] = s3 * yy;
    sh[3] = s3 * zz;
    sh[4] = s15 * xx * yy;
    sh[5] = s15 * yy * zz;
    sh[6] = 0.5f * s5 * (3.0f * zz * zz - r2);
    sh[7] = s15 * xx * zz;
    sh[8] = 0.5f * s15 * (xx * xx - yy * yy);
}

// Fused: w (per-block recompute), node1[v]=(px,py,pz,b0), node2[v]=(b1,b2), deg histogram.
__global__ void k_prep(const float* __restrict__ x,
                       const float* __restrict__ pos,
                       const float* __restrict__ W1_0, const float* __restrict__ W1_1,
                       const float* __restrict__ W1_2, const float* __restrict__ W2_0,
                       const float* __restrict__ W2_1, const float* __restrict__ W2_2,
                       const int* __restrict__ edst,
                       float4* __restrict__ node1, float2* __restrict__ node2,
                       int* __restrict__ deg, int n_nodes, int n_edges) {
    __shared__ float ws[90];
    int t = threadIdx.x;
    int g = blockIdx.x * blockDim.x + t;
    bool nodeBlock = (blockIdx.x * blockDim.x) < n_nodes;
    if (nodeBlock) {
        const float inv_s30 = 0.18257418583505536f;
        if (t < 30) {
            float s = 0.f;
            for (int u = 0; u < 64; u++) s += W1_0[t * 64 + u] * W2_0[u];
            ws[t] = s * inv_s30;
        } else if (t < 60) {
            int k = t - 30;
            float s = 0.f;
            for (int u = 0; u < 24; u++) s += W1_1[k * 24 + u] * W2_1[u];
            ws[t] = s * inv_s30;
        } else if (t < 90) {
            int k = t - 60;
            float s = 0.f;
            for (int u = 0; u < 16; u++) s += W1_2[k * 16 + u] * W2_2[u];
            ws[t] = s * inv_s30;
        }
        __syncthreads();
        if (g < n_nodes) {
            const float* xv = x + (size_t)g * 30;
            float s0 = 0.f, s1 = 0.f, s2 = 0.f;
#pragma unroll
            for (int k = 0; k < 30; k++) {
                float xk = xv[k];
                s0 += xk * ws[k];
                s1 += xk * ws[30 + k];
                s2 += xk * ws[60 + k];
            }
            node1[g] = make_float4(pos[g * 3 + 0], pos[g * 3 + 1], pos[g * 3 + 2], s0);
            node2[g] = make_float2(s1, s2);
        }
    }
    int e0 = 2 * g, e1 = 2 * g + 1;
    if (e1 < n_edges) {
        int2 d2 = ((const int2*)edst)[g];
        atomicAdd(deg + d2.x, 1);
        atomicAdd(deg + d2.y, 1);
    } else if (e0 < n_edges) {
        atomicAdd(deg + edst[e0], 1);
    }
}

// blocksum[b] = sum of deg over block b's 256 nodes
__global__ void k_scan1(const int* __restrict__ deg, int* __restrict__ blocksum, int n_nodes) {
    __shared__ int s[256];
    int t = threadIdx.x;
    int v = blockIdx.x * 256 + t;
    s[t] = (v < n_nodes) ? deg[v] : 0;
    __syncthreads();
    for (int off = 128; off > 0; off >>= 1) {
        if (t < off) s[t] += s[t + off];
        __syncthreads();
    }
    if (t == 0) blocksum[blockIdx.x] = s[0];
}

// exclusive scan of blocksum (nb <= 256) -> blockoff
__global__ void k_scan2(const int* __restrict__ blocksum, int* __restrict__ blockoff, int nb) {
    __shared__ int s[256];
    int t = threadIdx.x;
    int val = (t < nb) ? blocksum[t] : 0;
    s[t] = val;
    __syncthreads();
    for (int off = 1; off < 256; off <<= 1) {
        int y = (t >= off) ? s[t - off] : 0;
        __syncthreads();
        s[t] += y;
        __syncthreads();
    }
    if (t < nb) blockoff[t] = s[t] - val;
}

// rowptr[v] = blockoff[b] + exclusive-scan-within-block(deg); also atoms histogram (batch sorted)
__global__ void k_scan3(const int* __restrict__ deg, const int* __restrict__ blockoff,
                        int* __restrict__ rowptr, const int* __restrict__ batch,
                        int* __restrict__ atoms, int n_nodes) {
    __shared__ int s[256];
    __shared__ int hist[512];
    int t = threadIdx.x;
    int v = blockIdx.x * 256 + t;
    int val = (v < n_nodes) ? deg[v] : 0;
    s[t] = val;
    hist[t] = 0;
    hist[t + 256] = 0;
    __syncthreads();
    for (int off = 1; off < 256; off <<= 1) {
        int y = (t >= off) ? s[t - off] : 0;
        __syncthreads();
        s[t] += y;
        __syncthreads();
    }
    if (v < n_nodes) rowptr[v] = blockoff[blockIdx.x] + s[t] - val;
    int v0 = blockIdx.x * 256;
    if (v0 < n_nodes) {
        int molFirst = batch[v0];
        int vend = min(v0 + 255, n_nodes - 1);
        int molLast = batch[vend];
        if (v < n_nodes) atomicAdd(&hist[batch[v] - molFirst], 1);
        __syncthreads();
        for (int m = t; m <= molLast - molFirst; m += 256)
            if (hist[m] > 0) atomicAdd(atoms + molFirst + m, hist[m]);
    }
}

// slot = rowptr[dst] + cursor[dst]++;  rec[slot] = {src, ea}   (2 edges/thread)
__global__ void k_place(const float* __restrict__ eattr, const int* __restrict__ esrc,
                        const int* __restrict__ edst, const int* __restrict__ rowptr,
                        int* __restrict__ cursor, int2* __restrict__ rec, int n_edges) {
    int g = blockIdx.x * blockDim.x + threadIdx.x;
    int e0 = 2 * g, e1 = 2 * g + 1;
    if (e1 < n_edges) {
        int2 d2 = ((const int2*)edst)[g];
        int2 s2 = ((const int2*)esrc)[g];
        float ea0 = eattr[(size_t)e0 * 10];
        float ea1 = eattr[(size_t)e1 * 10];
        int slot0 = rowptr[d2.x] + atomicAdd(cursor + d2.x, 1);
        int slot1 = rowptr[d2.y] + atomicAdd(cursor + d2.y, 1);
        rec[slot0] = make_int2(s2.x, __float_as_int(ea0));
        rec[slot1] = make_int2(s2.y, __float_as_int(ea1));
    } else if (e0 < n_edges) {
        int dst = edst[e0];
        int slot = rowptr[dst] + atomicAdd(cursor + dst, 1);
        rec[slot] = make_int2(esrc[e0], __float_as_int(eattr[(size_t)e0 * 10]));
    }
}

// Pass A: 8 lanes per dst node.
// Pkg[v] = { P0..P3, P4..P7, P8, px, py, pz } (3 float4, all scaled by isd except pos).
__global__ void k_passA(const float4* __restrict__ node1, const float2* __restrict__ node2,
                        const int2* __restrict__ rec,
                        const int* __restrict__ rowptr, const int* __restrict__ deg,
                        float4* __restrict__ Pkg, int n_nodes) {
    int g = blockIdx.x * blockDim.x + threadIdx.x;
    int v = g >> 3, r = g & 7;
    if (v >= n_nodes) return;
    int beg = rowptr[v], d = deg[v];
    float4 pv = node1[v];
    float acc[9];
#pragma unroll
    for (int m = 0; m < 9; m++) acc[m] = 0.f;
    for (int i = beg + r; i < beg + d; i += 8) {
        int2 rcd = rec[i];
        int src = rcd.x;
        float ea = __int_as_float(rcd.y);
        float4 n1 = node1[src];
        float2 n2 = node2[src];
        float dx = n1.x - pv.x, dy = n1.y - pv.y, dz = n1.z - pv.z;
        float sh[9];
        sh_l012(dx, dy, dz, sh);
        acc[0] += ea * n1.w;  // sh[0]==1, b0 in n1.w
#pragma unroll
        for (int m = 1; m < 4; m++) acc[m] += ea * sh[m] * n2.x;
#pragma unroll
        for (int m = 4; m < 9; m++) acc[m] += ea * sh[m] * n2.y;
    }
#pragma unroll
    for (int off = 1; off < 8; off <<= 1)
#pragma unroll
        for (int m = 0; m < 9; m++) acc[m] += __shfl_xor(acc[m], off);
    if (r == 0) {
        float s = (d > 0) ? rsqrtf((float)d) : 0.f;
        float4* out = Pkg + (size_t)v * 3;
        out[0] = make_float4(acc[0] * s, acc[1] * s, acc[2] * s, acc[3] * s);
        out[1] = make_float4(acc[4] * s, acc[5] * s, acc[6] * s, acc[7] * s);
        out[2] = make_float4(acc[8] * s, pv.x, pv.y, pv.z);
    }
}

// Pass B: 8 lanes per dst node; LDS mol aggregation (smol[512] covers any batch range).
__global__ void k_passB(const float4* __restrict__ node1, const float4* __restrict__ Pkg,
                        const int2* __restrict__ rec,
                        const int* __restrict__ rowptr, const int* __restrict__ deg,
                        const int* __restrict__ batch,
                        float* __restrict__ accmol, int n_nodes) {
    __shared__ float smol[512];
    int t = threadIdx.x;
    smol[t] = 0.f;
    smol[t + 256] = 0.f;
    __syncthreads();
    int g = blockIdx.x * blockDim.x + t;
    int v = g >> 3, r = g & 7;
    int v0 = (blockIdx.x * blockDim.x) >> 3;  // 32 nodes per block
    const float i3 = 0.5773502691896258f;     // 1/sqrt(3)
    const float i5 = 0.4472135954999579f;     // 1/sqrt(5)
    const float i104 = 0.09805806756909202f;  // 1/sqrt(104)
    int molFirst = batch[min(v0, n_nodes - 1)];
    if (v < n_nodes) {
        int beg = rowptr[v], d = deg[v];
        float4 pv = node1[v];
        float s = 0.f;
        for (int i = beg + r; i < beg + d; i += 8) {
            int2 rcd = rec[i];
            int src = rcd.x;
            float ea = __int_as_float(rcd.y);
            const float4* Ps = Pkg + (size_t)src * 3;
            float4 p03 = Ps[0];
            float4 p47 = Ps[1];
            float4 p8p = Ps[2];
            float dx = p8p.y - pv.x, dy = p8p.z - pv.y, dz = p8p.w - pv.z;
            float sh[9];
            sh_l012(dx, dy, dz, sh);
            float t1 = sh[1] * p03.y + sh[2] * p03.z + sh[3] * p03.w;
            float t2 = sh[4] * p47.x + sh[5] * p47.y + sh[6] * p47.z + sh[7] * p47.w + sh[8] * p8p.x;
            s += ea * (p03.x + t1 * i3 + t2 * i5);
        }
#pragma unroll
        for (int off = 1; off < 8; off <<= 1) s += __shfl_xor(s, off);
        if (r == 0) {
            float isd = (d > 0) ? rsqrtf((float)d) : 0.f;
            atomicAdd(&smol[batch[v] - molFirst], s * i104 * isd);
        }
    }
    __syncthreads();
    if (v0 < n_nodes) {
        int vend = min(v0 + 31, n_nodes - 1);
        int nm = batch[vend] - molFirst + 1;
        for (int m = t; m < nm; m += 256) {
            float val = smol[m];
            if (val != 0.f) atomicAdd(accmol + molFirst + m, val);
        }
    }
}

__global__ void k_final(const float* __restrict__ acc, const int* __restrict__ atoms,
                        float* __restrict__ out, int n_mol) {
    int m = blockIdx.x * blockDim.x + threadIdx.x;
    if (m >= n_mol) return;
    int a = atoms[m];
    out[m] = (a > 0) ? acc[m] * rsqrtf((float)a) : 0.f;
}

extern "C" void kernel_launch(void* const* d_in, const int* in_sizes, int n_in,
                              void* d_out, int out_size, void* d_ws, size_t ws_size,
                              hipStream_t stream) {
    const float* pos   = (const float*)d_in[0];
    const float* x     = (const float*)d_in[1];
    const float* eattr = (const float*)d_in[2];
    const float* W1_0  = (const float*)d_in[3];
    const float* W1_1  = (const float*)d_in[4];
    const float* W1_2  = (const float*)d_in[5];
    const float* W2_0  = (const float*)d_in[6];
    const float* W2_1  = (const float*)d_in[7];
    const float* W2_2  = (const float*)d_in[8];
    const int* esrc  = (const int*)d_in[9];
    const int* edst  = (const int*)d_in[10];
    const int* batch = (const int*)d_in[11];

    const int n_edges = in_sizes[9];       // 600000
    const int n_nodes = in_sizes[11];      // 50000
    const int n_mol   = out_size;          // 512
    float* out = (float*)d_out;

    const int BS = 256;
    const int NB = (n_nodes + BS - 1) / BS;            // 196 (<= 256 for k_scan2)
    const int EB2 = (n_edges / 2 + BS - 1) / BS;       // 2 edges/thread
    const int VB8 = (8 * n_nodes + BS - 1) / BS;       // 8 lanes/node

    // Workspace layout; zeroed regions first.
    char* ws = (char*)d_ws;
    size_t off = 0;
    auto carve = [&](size_t bytes) {
        size_t o = off;
        off = (off + bytes + 255) & ~(size_t)255;
        return o;
    };
    size_t off_deg    = carve((size_t)n_nodes * sizeof(int));
    size_t off_cur    = carve((size_t)n_nodes * sizeof(int));
    size_t off_acc    = carve((size_t)n_mol * sizeof(float));
    size_t off_atoms  = carve((size_t)n_mol * sizeof(int));
    size_t zero_bytes = off;
    size_t off_rowptr = carve((size_t)n_nodes * sizeof(int));
    size_t off_bsum   = carve((size_t)NB * sizeof(int));
    size_t off_boff   = carve((size_t)NB * sizeof(int));
    size_t off_n1     = carve((size_t)n_nodes * sizeof(float4));
    size_t off_n2     = carve((size_t)n_nodes * sizeof(float2));
    size_t off_Pkg    = carve((size_t)n_nodes * 3 * sizeof(float4));
    size_t off_rec    = carve((size_t)n_edges * sizeof(int2));
    (void)ws_size;

    int*    deg    = (int*)(ws + off_deg);
    int*    cursor = (int*)(ws + off_cur);
    float*  accmol = (float*)(ws + off_acc);
    int*    atoms  = (int*)(ws + off_atoms);
    int*    rowptr = (int*)(ws + off_rowptr);
    int*    bsum   = (int*)(ws + off_bsum);
    int*    boff   = (int*)(ws + off_boff);
    float4* node1  = (float4*)(ws + off_n1);
    float2* node2  = (float2*)(ws + off_n2);
    float4* Pkg    = (float4*)(ws + off_Pkg);
    int2*   rec    = (int2*)(ws + off_rec);

    hipMemsetAsync(d_ws, 0, zero_bytes, stream);

    k_prep<<<EB2, BS, 0, stream>>>(x, pos, W1_0, W1_1, W1_2, W2_0, W2_1, W2_2,
                                   edst, node1, node2, deg, n_nodes, n_edges);
    k_scan1<<<NB, BS, 0, stream>>>(deg, bsum, n_nodes);
    k_scan2<<<1, 256, 0, stream>>>(bsum, boff, NB);
    k_scan3<<<NB, BS, 0, stream>>>(deg, boff, rowptr, batch, atoms, n_nodes);
    k_place<<<EB2, BS, 0, stream>>>(eattr, esrc, edst, rowptr, cursor, rec, n_edges);
    k_passA<<<VB8, BS, 0, stream>>>(node1, node2, rec, rowptr, deg, Pkg, n_nodes);
    k_passB<<<VB8, BS, 0, stream>>>(node1, Pkg, rec, rowptr, deg, batch, accmol, n_nodes);
    k_final<<<(n_mol + BS - 1) / BS, BS, 0, stream>>>(accmol, atoms, out, n_mol);
}

// Round 6
// 162.020 us; speedup vs baseline: 3.1345x; 1.1200x over previous
//
#include <hip/hip_runtime.h>

#define DEV_INLINE __device__ __forceinline__

// sh[0..8]: l=0,1,2 real spherical harmonics as in reference _sh (first 9 comps)
static DEV_INLINE void sh_l012(float xx, float yy, float zz, float sh[9]) {
    const float s3  = 1.7320508075688772f;
    const float s5  = 2.23606797749979f;
    const float s15 = 3.872983346207417f;
    float r2 = xx * xx + yy * yy + zz * zz;
    sh[0] = 1.0f;
    sh[1] = s3 * xx;
    sh[2] = s3 * yy;
    sh[3] = s3 * zz;
    sh[4] = s15 * xx * yy;
    sh[5] = s15 * yy * zz;
    sh[6] = 0.5f * s5 * (3.0f * zz * zz - r2);
    sh[7] = s15 * xx * zz;
    sh[8] = 0.5f * s15 * (xx * xx - yy * yy);
}

// Fused: node1[v]=(px,py,pz,b0), node2[v]=(b1,b2); edge pass: rank_e=deg[dst]++ (returning),
// cache ea_e compactly. edst/eattr are read exactly once here.
__global__ void k_prep(const float* __restrict__ x,
                       const float* __restrict__ pos,
                       const float* __restrict__ W1_0, const float* __restrict__ W1_1,
                       const float* __restrict__ W1_2, const float* __restrict__ W2_0,
                       const float* __restrict__ W2_1, const float* __restrict__ W2_2,
                       const int* __restrict__ edst, const float* __restrict__ eattr,
                       float4* __restrict__ node1, float2* __restrict__ node2,
                       int* __restrict__ deg, int* __restrict__ rank, float* __restrict__ eac,
                       int n_nodes, int n_edges) {
    __shared__ float ws[90];
    int t = threadIdx.x;
    int g = blockIdx.x * blockDim.x + t;
    bool nodeBlock = (blockIdx.x * blockDim.x) < n_nodes;  // uniform per block
    if (nodeBlock) {
        const float inv_s30 = 0.18257418583505536f;
        if (t < 30) {
            float s = 0.f;
            for (int u = 0; u < 64; u++) s += W1_0[t * 64 + u] * W2_0[u];
            ws[t] = s * inv_s30;
        } else if (t < 60) {
            int k = t - 30;
            float s = 0.f;
            for (int u = 0; u < 24; u++) s += W1_1[k * 24 + u] * W2_1[u];
            ws[t] = s * inv_s30;
        } else if (t < 90) {
            int k = t - 60;
            float s = 0.f;
            for (int u = 0; u < 16; u++) s += W1_2[k * 16 + u] * W2_2[u];
            ws[t] = s * inv_s30;
        }
        __syncthreads();
        if (g < n_nodes) {
            const float* xv = x + (size_t)g * 30;
            float s0 = 0.f, s1 = 0.f, s2 = 0.f;
#pragma unroll
            for (int k = 0; k < 30; k++) {
                float xk = xv[k];
                s0 += xk * ws[k];
                s1 += xk * ws[30 + k];
                s2 += xk * ws[60 + k];
            }
            node1[g] = make_float4(pos[g * 3 + 0], pos[g * 3 + 1], pos[g * 3 + 2], s0);
            node2[g] = make_float2(s1, s2);
        }
    }
    int e0 = 2 * g, e1 = 2 * g + 1;
    if (e1 < n_edges) {
        int2 d2 = ((const int2*)edst)[g];
        float ea0 = eattr[(size_t)e0 * 10];
        float ea1 = eattr[(size_t)e1 * 10];
        int r0 = atomicAdd(deg + d2.x, 1);
        int r1 = atomicAdd(deg + d2.y, 1);
        ((int2*)rank)[g] = make_int2(r0, r1);
        ((float2*)eac)[g] = make_float2(ea0, ea1);
    } else if (e0 < n_edges) {
        float ea0 = eattr[(size_t)e0 * 10];
        rank[e0] = atomicAdd(deg + edst[e0], 1);
        eac[e0] = ea0;
    }
}

// One-kernel scan: per-block local exclusive prefix -> rowptr_local, block sums -> bsum;
// atoms histogram; last-done block scans bsum (NB<=256) -> blockoff.
__global__ void k_scan(const int* __restrict__ deg, const int* __restrict__ batch,
                       int* __restrict__ rowptr_local, int* __restrict__ bsum,
                       int* __restrict__ blockoff, int* __restrict__ atoms,
                       int* __restrict__ done, int n_nodes) {
    __shared__ int s[256];
    __shared__ int hist[512];
    __shared__ int lastFlag;
    int t = threadIdx.x;
    int v = blockIdx.x * 256 + t;
    int val = (v < n_nodes) ? deg[v] : 0;
    s[t] = val;
    hist[t] = 0;
    hist[t + 256] = 0;
    __syncthreads();
    for (int off = 1; off < 256; off <<= 1) {
        int y = (t >= off) ? s[t - off] : 0;
        __syncthreads();
        s[t] += y;
        __syncthreads();
    }
    if (v < n_nodes) rowptr_local[v] = s[t] - val;  // exclusive local prefix
    if (t == 255) bsum[blockIdx.x] = s[255];        // block total
    // atoms-per-mol histogram (batch sorted => small span per block)
    int v0 = blockIdx.x * 256;
    int molFirst = batch[min(v0, n_nodes - 1)];
    if (v < n_nodes) atomicAdd(&hist[batch[v] - molFirst], 1);
    __syncthreads();
    int vend = min(v0 + 255, n_nodes - 1);
    int molLast = batch[vend];
    for (int m = t; m <= molLast - molFirst; m += 256)
        if (hist[m] > 0) atomicAdd(atoms + molFirst + m, hist[m]);
    // last-done block scans the block sums
    if (t == 0) {
        __threadfence();
        lastFlag = (atomicAdd(done, 1) == gridDim.x - 1) ? 1 : 0;
    }
    __syncthreads();
    if (lastFlag) {
        int nb = gridDim.x;
        int bv = (t < nb) ? bsum[t] : 0;
        s[t] = bv;
        __syncthreads();
        for (int off = 1; off < 256; off <<= 1) {
            int y = (t >= off) ? s[t - off] : 0;
            __syncthreads();
            s[t] += y;
            __syncthreads();
        }
        if (t < nb) blockoff[t] = s[t] - bv;
    }
}

// Placement, no atomics: slot = rowptr_local[dst] + blockoff[dst>>8] + rank_e.
__global__ void k_place(const int* __restrict__ esrc, const int* __restrict__ edst,
                        const int* __restrict__ rank, const float* __restrict__ eac,
                        const int* __restrict__ rowptr_local, const int* __restrict__ blockoff,
                        int2* __restrict__ rec, int n_edges) {
    int g = blockIdx.x * blockDim.x + threadIdx.x;
    int e0 = 2 * g, e1 = 2 * g + 1;
    if (e1 < n_edges) {
        int2 d2 = ((const int2*)edst)[g];
        int2 s2 = ((const int2*)esrc)[g];
        int2 r2 = ((const int2*)rank)[g];
        float2 ea2 = ((const float2*)eac)[g];
        int slot0 = rowptr_local[d2.x] + blockoff[d2.x >> 8] + r2.x;
        int slot1 = rowptr_local[d2.y] + blockoff[d2.y >> 8] + r2.y;
        rec[slot0] = make_int2(s2.x, __float_as_int(ea2.x));
        rec[slot1] = make_int2(s2.y, __float_as_int(ea2.y));
    } else if (e0 < n_edges) {
        int dst = edst[e0];
        int slot = rowptr_local[dst] + blockoff[dst >> 8] + rank[e0];
        rec[slot] = make_int2(esrc[e0], __float_as_int(eac[e0]));
    }
}

// Pass A: 16 lanes per dst node.
// Pkg[v] = { P0..P3, P4..P7, P8, px, py, pz } (3 float4; P scaled by isd).
__global__ void k_passA(const float4* __restrict__ node1, const float2* __restrict__ node2,
                        const int2* __restrict__ rec,
                        const int* __restrict__ rowptr_local, const int* __restrict__ blockoff,
                        const int* __restrict__ deg,
                        float4* __restrict__ Pkg, int n_nodes) {
    int g = blockIdx.x * blockDim.x + threadIdx.x;
    int v = g >> 4, r = g & 15;
    if (v >= n_nodes) return;
    int beg = rowptr_local[v] + blockoff[v >> 8];
    int d = deg[v];
    float4 pv = node1[v];
    float acc[9];
#pragma unroll
    for (int m = 0; m < 9; m++) acc[m] = 0.f;
    for (int i = beg + r; i < beg + d; i += 16) {
        int2 rcd = rec[i];
        int src = rcd.x;
        float ea = __int_as_float(rcd.y);
        float4 n1 = node1[src];
        float2 n2 = node2[src];
        float dx = n1.x - pv.x, dy = n1.y - pv.y, dz = n1.z - pv.z;
        float sh[9];
        sh_l012(dx, dy, dz, sh);
        acc[0] += ea * n1.w;  // sh[0]==1, b0 in n1.w
#pragma unroll
        for (int m = 1; m < 4; m++) acc[m] += ea * sh[m] * n2.x;
#pragma unroll
        for (int m = 4; m < 9; m++) acc[m] += ea * sh[m] * n2.y;
    }
#pragma unroll
    for (int off = 1; off < 16; off <<= 1)
#pragma unroll
        for (int m = 0; m < 9; m++) acc[m] += __shfl_xor(acc[m], off);
    if (r == 0) {
        float s = (d > 0) ? rsqrtf((float)d) : 0.f;
        float4* out = Pkg + (size_t)v * 3;
        out[0] = make_float4(acc[0] * s, acc[1] * s, acc[2] * s, acc[3] * s);
        out[1] = make_float4(acc[4] * s, acc[5] * s, acc[6] * s, acc[7] * s);
        out[2] = make_float4(acc[8] * s, pv.x, pv.y, pv.z);
    }
}

// Pass B: 16 lanes per dst node; LDS mol aggregation, one flush atomic per touched mol.
__global__ void k_passB(const float4* __restrict__ node1, const float4* __restrict__ Pkg,
                        const int2* __restrict__ rec,
                        const int* __restrict__ rowptr_local, const int* __restrict__ blockoff,
                        const int* __restrict__ deg, const int* __restrict__ batch,
                        float* __restrict__ accmol, int n_nodes) {
    __shared__ float smol[512];
    int t = threadIdx.x;
    smol[t] = 0.f;
    smol[t + 256] = 0.f;
    __syncthreads();
    int g = blockIdx.x * blockDim.x + t;
    int v = g >> 4, r = g & 15;
    int v0 = blockIdx.x * 16;                 // 16 nodes per block
    const float i3 = 0.5773502691896258f;     // 1/sqrt(3)
    const float i5 = 0.4472135954999579f;     // 1/sqrt(5)
    const float i104 = 0.09805806756909202f;  // 1/sqrt(104)
    int molFirst = batch[min(v0, n_nodes - 1)];
    if (v < n_nodes) {
        int beg = rowptr_local[v] + blockoff[v >> 8];
        int d = deg[v];
        float4 pv = node1[v];
        float s = 0.f;
        for (int i = beg + r; i < beg + d; i += 16) {
            int2 rcd = rec[i];
            int src = rcd.x;
            float ea = __int_as_float(rcd.y);
            const float4* Ps = Pkg + (size_t)src * 3;
            float4 p03 = Ps[0];
            float4 p47 = Ps[1];
            float4 p8p = Ps[2];
            float dx = p8p.y - pv.x, dy = p8p.z - pv.y, dz = p8p.w - pv.z;
            float sh[9];
            sh_l012(dx, dy, dz, sh);
            float t1 = sh[1] * p03.y + sh[2] * p03.z + sh[3] * p03.w;
            float t2 = sh[4] * p47.x + sh[5] * p47.y + sh[6] * p47.z + sh[7] * p47.w + sh[8] * p8p.x;
            s += ea * (p03.x + t1 * i3 + t2 * i5);
        }
#pragma unroll
        for (int off = 1; off < 16; off <<= 1) s += __shfl_xor(s, off);
        if (r == 0) {
            float isd = (d > 0) ? rsqrtf((float)d) : 0.f;
            atomicAdd(&smol[batch[v] - molFirst], s * i104 * isd);
        }
    }
    __syncthreads();
    if (v0 < n_nodes) {
        int vend = min(v0 + 15, n_nodes - 1);
        int nm = batch[vend] - molFirst + 1;
        for (int m = t; m < nm; m += 256) {
            float val = smol[m];
            if (val != 0.f) atomicAdd(accmol + molFirst + m, val);
        }
    }
}

__global__ void k_final(const float* __restrict__ acc, const int* __restrict__ atoms,
                        float* __restrict__ out, int n_mol) {
    int m = blockIdx.x * blockDim.x + threadIdx.x;
    if (m >= n_mol) return;
    int a = atoms[m];
    out[m] = (a > 0) ? acc[m] * rsqrtf((float)a) : 0.f;
}

extern "C" void kernel_launch(void* const* d_in, const int* in_sizes, int n_in,
                              void* d_out, int out_size, void* d_ws, size_t ws_size,
                              hipStream_t stream) {
    const float* pos   = (const float*)d_in[0];
    const float* x     = (const float*)d_in[1];
    const float* eattr = (const float*)d_in[2];
    const float* W1_0  = (const float*)d_in[3];
    const float* W1_1  = (const float*)d_in[4];
    const float* W1_2  = (const float*)d_in[5];
    const float* W2_0  = (const float*)d_in[6];
    const float* W2_1  = (const float*)d_in[7];
    const float* W2_2  = (const float*)d_in[8];
    const int* esrc  = (const int*)d_in[9];
    const int* edst  = (const int*)d_in[10];
    const int* batch = (const int*)d_in[11];

    const int n_edges = in_sizes[9];       // 600000
    const int n_nodes = in_sizes[11];      // 50000
    const int n_mol   = out_size;          // 512
    float* out = (float*)d_out;

    const int BS = 256;
    const int NB = (n_nodes + BS - 1) / BS;            // 196 (<= 256 for last-block scan)
    const int EB2 = (n_edges / 2 + BS - 1) / BS;       // 2 edges/thread
    const int VB16 = (16 * n_nodes + BS - 1) / BS;     // 16 lanes/node

    // Workspace layout; zeroed regions first.
    char* ws = (char*)d_ws;
    size_t off = 0;
    auto carve = [&](size_t bytes) {
        size_t o = off;
        off = (off + bytes + 255) & ~(size_t)255;
        return o;
    };
    size_t off_deg    = carve((size_t)n_nodes * sizeof(int));
    size_t off_acc    = carve((size_t)n_mol * sizeof(float));
    size_t off_atoms  = carve((size_t)n_mol * sizeof(int));
    size_t off_done   = carve(sizeof(int));
    size_t zero_bytes = off;
    size_t off_rpl    = carve((size_t)n_nodes * sizeof(int));
    size_t off_bsum   = carve((size_t)NB * sizeof(int));
    size_t off_boff   = carve((size_t)NB * sizeof(int));
    size_t off_n1     = carve((size_t)n_nodes * sizeof(float4));
    size_t off_n2     = carve((size_t)n_nodes * sizeof(float2));
    size_t off_Pkg    = carve((size_t)n_nodes * 3 * sizeof(float4));
    size_t off_rec    = carve((size_t)n_edges * sizeof(int2));
    size_t off_rank   = carve((size_t)n_edges * sizeof(int));
    size_t off_eac    = carve((size_t)n_edges * sizeof(float));
    (void)ws_size;

    int*    deg    = (int*)(ws + off_deg);
    float*  accmol = (float*)(ws + off_acc);
    int*    atoms  = (int*)(ws + off_atoms);
    int*    done   = (int*)(ws + off_done);
    int*    rpl    = (int*)(ws + off_rpl);
    int*    bsum   = (int*)(ws + off_bsum);
    int*    boff   = (int*)(ws + off_boff);
    float4* node1  = (float4*)(ws + off_n1);
    float2* node2  = (float2*)(ws + off_n2);
    float4* Pkg    = (float4*)(ws + off_Pkg);
    int2*   rec    = (int2*)(ws + off_rec);
    int*    rank   = (int*)(ws + off_rank);
    float*  eac    = (float*)(ws + off_eac);

    hipMemsetAsync(d_ws, 0, zero_bytes, stream);

    k_prep<<<EB2, BS, 0, stream>>>(x, pos, W1_0, W1_1, W1_2, W2_0, W2_1, W2_2,
                                   edst, eattr, node1, node2, deg, rank, eac,
                                   n_nodes, n_edges);
    k_scan<<<NB, BS, 0, stream>>>(deg, batch, rpl, bsum, boff, atoms, done, n_nodes);
    k_place<<<EB2, BS, 0, stream>>>(esrc, edst, rank, eac, rpl, boff, rec, n_edges);
    k_passA<<<VB16, BS, 0, stream>>>(node1, node2, rec, rpl, boff, deg, Pkg, n_nodes);
    k_passB<<<VB16, BS, 0, stream>>>(node1, Pkg, rec, rpl, boff, deg, batch, accmol, n_nodes);
    k_final<<<(n_mol + BS - 1) / BS, BS, 0, stream>>>(accmol, atoms, out, n_mol);
}